// Round 12
// baseline (2385.604 us; speedup 1.0000x reference)
//
#include <hip/hip_runtime.h>
#include <math.h>

#define NN 16384
#define EE 262144
#define HH 256

#define INV_SQRT_3f 0.57735026918962576f
#define INV_SQRT_Hf 0.0625f
#define INV_SQRT_2f 0.70710678118654752f
#define SSILU_SCALE 1.6666666666666667f

typedef __attribute__((ext_vector_type(8))) short bf16x8;
typedef __attribute__((ext_vector_type(4))) float f32x4;

__device__ __forceinline__ float ssilu_f(float v) {
    return v * (1.0f / (1.0f + __expf(-v))) * SSILU_SCALE;
}
__device__ __forceinline__ float b2f(short s) {
    unsigned int u = ((unsigned int)(unsigned short)s) << 16;
    return __uint_as_float(u);
}
__device__ __forceinline__ short f2b(float f) {
    unsigned int u = __float_as_uint(f);
    unsigned int r = (u + 0x7fff + ((u >> 16) & 1)) >> 16;
    return (short)r;
}
// fp32x8 -> split hi/lo bf16x8 in registers (same rounding as the old split4)
__device__ __forceinline__ void cvt8(float4 a, float4 b, bf16x8& h, bf16x8& l) {
    float v[8] = {a.x, a.y, a.z, a.w, b.x, b.y, b.z, b.w};
    #pragma unroll
    for (int j = 0; j < 8; j++) {
        short hh = f2b(v[j]);
        h[j] = hh;
        l[j] = f2b(v[j] - b2f(hh));
    }
}
// same, from native ext-vector f32x4 (usable with __builtin_nontemporal_load)
__device__ __forceinline__ void cvt8v(f32x4 a, f32x4 b, bf16x8& h, bf16x8& l) {
    float v[8] = {a.x, a.y, a.z, a.w, b.x, b.y, b.z, b.w};
    #pragma unroll
    for (int j = 0; j < 8; j++) {
        short hh = f2b(v[j]);
        h[j] = hh;
        l[j] = f2b(v[j] - b2f(hh));
    }
}

// ---------------- LayerNorm: one block per row, fp32 out + x1/vecacc init ------
__global__ void __launch_bounds__(256) ln_kernel(const float* __restrict__ x,
                                                 const float* __restrict__ vec,
                                                 const float* __restrict__ g,
                                                 const float* __restrict__ b,
                                                 float* __restrict__ o_,
                                                 float* __restrict__ x1,
                                                 float* __restrict__ vecacc) {
    int n = blockIdx.x;
    int t = threadIdx.x;
    float v = x[(long)n * HH + t];
    x1[(long)n * HH + t] = v;
    long vb = (long)n * 768 + t;
    vecacc[vb]       = vec[vb];
    vecacc[vb + 256] = vec[vb + 256];
    vecacc[vb + 512] = vec[vb + 512];
    float s = v, s2 = v * v;
    #pragma unroll
    for (int off = 32; off > 0; off >>= 1) {
        s  += __shfl_down(s, off);
        s2 += __shfl_down(s2, off);
    }
    __shared__ float red[8];
    int wave = t >> 6, lane = t & 63;
    if (lane == 0) { red[wave] = s; red[4 + wave] = s2; }
    __syncthreads();
    __shared__ float mr[2];
    if (t == 0) {
        float ts = red[0] + red[1] + red[2] + red[3];
        float ts2 = red[4] + red[5] + red[6] + red[7];
        float mean = ts * (1.0f / HH);
        float var = ts2 * (1.0f / HH) - mean * mean;
        mr[0] = mean;
        mr[1] = rsqrtf(var + 1e-5f);
    }
    __syncthreads();
    o_[(long)n * HH + t] = (v - mr[0]) * mr[1] * g[t] + b[t];
}

// ---- ALL weight transposes + hi/lo splits in ONE kernel (incl. W_rbf) ----
struct WtArgs {
    const float* W[12];
    int K[12];
    int N[12];
    int off[13];   // cumulative element offsets; off[12] = total
};

__global__ void __launch_bounds__(256) wt_split_all(WtArgs a,
                                                    short* __restrict__ WTh,
                                                    short* __restrict__ WTl) {
    int idx = blockIdx.x * 256 + threadIdx.x;
    int s = 0;
    #pragma unroll
    for (int i = 1; i < 12; i++) s += (idx >= a.off[i]) ? 1 : 0;
    int local = idx - a.off[s];
    int K = a.K[s], N = a.N[s];
    int k = local / N, n = local - k * N;
    float w = a.W[s][local];
    short hh = f2b(w);
    long o = (long)a.off[s] + (long)n * K + k;
    WTh[o] = hh;
    WTl[o] = f2b(w - b2f(hh));
}

// ---- split-bf16 MFMA GEMM v3: fp32 A, in-register hi/lo split ----
// act 0: fp32 out C1          act 1: ssilu + fp32 out C1
// act 2: bf16 out C1          act 3: split out (C1 hi, C2 lo)
// act 4: col<256 -> fp32 C1[row*256+col]; col>=256 -> bf16 C2[row*256+col-256]
// act 5: col<256 -> bf16 C1[row*256+col]; col>=256 -> fp32 C2[row*128+col-256]
__global__ void __launch_bounds__(256) mfma_gemm(const float* __restrict__ A,
                                                 const short* __restrict__ Wh,
                                                 const short* __restrict__ Wl,
                                                 const float* __restrict__ bias,
                                                 void* __restrict__ C1,
                                                 void* __restrict__ C2,
                                                 int M, int K, int N, int act) {
    int tid = threadIdx.x;
    int wave = tid >> 6, lane = tid & 63;
    int quad = lane >> 4, l16 = lane & 15;
    long bm = (long)blockIdx.x * 128 + wave * 32;
    long bn = (long)blockIdx.y * 64;
    long a0 = (bm + l16) * K + quad * 8;
    long a1 = a0 + (long)16 * K;
    long w0 = (bn + l16) * K + quad * 8;

    f32x4 acc[2][4];
    #pragma unroll
    for (int f = 0; f < 2; f++)
        #pragma unroll
        for (int t = 0; t < 4; t++) acc[f][t] = (f32x4){0.f, 0.f, 0.f, 0.f};

    bf16x8 cah[2], cal[2], cbh[4], cbl[4];
    cvt8(*(const float4*)(A + a0), *(const float4*)(A + a0 + 4), cah[0], cal[0]);
    cvt8(*(const float4*)(A + a1), *(const float4*)(A + a1 + 4), cah[1], cal[1]);
    #pragma unroll
    for (int t = 0; t < 4; t++) {
        long wo = w0 + (long)t * 16 * K;
        cbh[t] = *(const bf16x8*)(Wh + wo);
        cbl[t] = *(const bf16x8*)(Wl + wo);
    }

    for (int k0 = 0; k0 < K; k0 += 32) {
        int k1 = k0 + 32;
        float4 n0a, n0b, n1a, n1b;
        bf16x8 nbh[4], nbl[4];
        if (k1 < K) {
            n0a = *(const float4*)(A + a0 + k1);
            n0b = *(const float4*)(A + a0 + k1 + 4);
            n1a = *(const float4*)(A + a1 + k1);
            n1b = *(const float4*)(A + a1 + k1 + 4);
            #pragma unroll
            for (int t = 0; t < 4; t++) {
                long wo = w0 + (long)t * 16 * K + k1;
                nbh[t] = *(const bf16x8*)(Wh + wo);
                nbl[t] = *(const bf16x8*)(Wl + wo);
            }
        }
        #pragma unroll
        for (int t = 0; t < 4; t++) {
            #pragma unroll
            for (int f = 0; f < 2; f++) {
                acc[f][t] = __builtin_amdgcn_mfma_f32_16x16x32_bf16(cah[f], cbh[t], acc[f][t], 0, 0, 0);
                acc[f][t] = __builtin_amdgcn_mfma_f32_16x16x32_bf16(cal[f], cbh[t], acc[f][t], 0, 0, 0);
                acc[f][t] = __builtin_amdgcn_mfma_f32_16x16x32_bf16(cah[f], cbl[t], acc[f][t], 0, 0, 0);
            }
        }
        if (k1 < K) {
            cvt8(n0a, n0b, cah[0], cal[0]);
            cvt8(n1a, n1b, cah[1], cal[1]);
            #pragma unroll
            for (int t = 0; t < 4; t++) { cbh[t] = nbh[t]; cbl[t] = nbl[t]; }
        }
    }

    #pragma unroll
    for (int f = 0; f < 2; f++) {
        long row0 = bm + f * 16 + quad * 4;
        #pragma unroll
        for (int t = 0; t < 4; t++) {
            long col = bn + t * 16 + l16;
            float bv = bias ? bias[col] : 0.f;
            #pragma unroll
            for (int r = 0; r < 4; r++) {
                float v = acc[f][t][r] + bv;
                long row = row0 + r;
                if (act == 4) {
                    if (col < 256) ((float*)C1)[row * 256 + col] = v;
                    else           ((short*)C2)[row * 256 + col - 256] = f2b(v);
                } else if (act == 5) {
                    if (col < 256) ((short*)C1)[row * 256 + col] = f2b(v);
                    else           ((float*)C2)[row * 128 + col - 256] = v;
                } else {
                    long idx = row * N + col;
                    if (act == 3) {
                        short hh = f2b(v);
                        ((short*)C1)[idx] = hh;
                        ((short*)C2)[idx] = f2b(v - b2f(hh));
                    } else if (act == 2) {
                        ((short*)C1)[idx] = f2b(v);
                    } else {
                        if (act == 1) v = ssilu_f(v);
                        ((float*)C1)[idx] = v;
                    }
                }
            }
        }
    }
}

// ---------------- edge sort (counting sort by dst) ----------------
__global__ void __launch_bounds__(256) zero_kernel(int* __restrict__ p, int n) {
    int i = blockIdx.x * 256 + threadIdx.x;
    if (i < n) p[i] = 0;
}

__global__ void __launch_bounds__(256) hist_kernel(const int* __restrict__ eidx,
                                                   int* __restrict__ cnt) {
    int e = blockIdx.x * 256 + threadIdx.x;
    atomicAdd(&cnt[eidx[EE + e]], 1);
}

__global__ void __launch_bounds__(256) scan_kernel(int* __restrict__ cursor,
                                                   int* __restrict__ rowptr) {
    int t = threadIdx.x;
    int base_i = t * 64;
    int tsum = 0;
    for (int i = 0; i < 64; i++) tsum += cursor[base_i + i];
    __shared__ int ls[256];
    ls[t] = tsum;
    __syncthreads();
    for (int off = 1; off < 256; off <<= 1) {
        int v = (t >= off) ? ls[t - off] : 0;
        __syncthreads();
        ls[t] += v;
        __syncthreads();
    }
    int running = ls[t] - tsum;
    for (int i = 0; i < 64; i++) {
        int c = cursor[base_i + i];
        rowptr[base_i + i] = running;
        cursor[base_i + i] = running;
        running += c;
    }
    if (t == 255) rowptr[NN] = running;
}

// scatter: also materialize dst/src/ev in sorted order for the edge kernel
__global__ void __launch_bounds__(256) scatter_kernel(const int* __restrict__ eidx,
                                                      const float* __restrict__ ev,
                                                      int* __restrict__ cursor,
                                                      int* __restrict__ perm,
                                                      int* __restrict__ dsts,
                                                      int* __restrict__ srcs,
                                                      float* __restrict__ evs) {
    int e = blockIdx.x * 256 + threadIdx.x;
    int s_ = eidx[e];
    int d_ = eidx[EE + e];
    int pos = atomicAdd(&cursor[d_], 1);
    perm[pos] = e;
    dsts[pos] = d_;
    srcs[pos] = s_;
    evs[pos * 3 + 0] = ev[e * 3 + 0];
    evs[pos * 3 + 1] = ev[e * 3 + 1];
    evs[pos * 3 + 2] = ev[e * 3 + 2];
}

// one 16x64 MFMA tile of rbfh into this wave's rows of mlds
__device__ __forceinline__ void mfma_tile(int bn, int base, int quad, int l16,
                                          const bf16x8 (&afh)[2],
                                          const bf16x8 (&afl)[2],
                                          const short* __restrict__ Wrh,
                                          const short* __restrict__ Wrl,
                                          const float* __restrict__ b_rbf,
                                          float (*mlds)[66]) {
    f32x4 acc[4];
    #pragma unroll
    for (int t = 0; t < 4; t++) {
        float bv = b_rbf[bn + t * 16 + l16];
        acc[t] = (f32x4){bv, bv, bv, bv};
        #pragma unroll
        for (int ks = 0; ks < 2; ks++) {
            long wo = (long)(bn + t * 16 + l16) * 64 + ks * 32 + quad * 8;
            bf16x8 bh = *(const bf16x8*)(Wrh + wo);
            bf16x8 bl = *(const bf16x8*)(Wrl + wo);
            acc[t] = __builtin_amdgcn_mfma_f32_16x16x32_bf16(afh[ks], bh, acc[t], 0, 0, 0);
            acc[t] = __builtin_amdgcn_mfma_f32_16x16x32_bf16(afl[ks], bh, acc[t], 0, 0, 0);
            acc[t] = __builtin_amdgcn_mfma_f32_16x16x32_bf16(afh[ks], bl, acc[t], 0, 0, 0);
        }
    }
    #pragma unroll
    for (int t = 0; t < 4; t++)
        #pragma unroll
        for (int r = 0; r < 4; r++)
            mlds[base + quad * 4 + r][t * 16 + l16] = acc[t][r];
}

// ---------------- Edge-parallel fused rbf-GEMM + gather + atomic reduce -------
// v8: merged sec1+sec2 atomics (round-11's proven WRITE_SIZE halving) WITHOUT
// the VGPR cliff. pm3 array eliminated — the m3 product is computed inline in
// the 4-row batch loop from mlds (which holds the m3 tile after its MFMA
// overwrote m2; pm2 was fully staged before that). Peak live ~= pm2[16]+p[12].
// __launch_bounds__(512, 8) pins VGPR <= 64 so occupancy stays at round-10
// levels; 3 atomics/run instead of 6.
__global__ void __launch_bounds__(512, 8) edge_gather_kernel(
        const float* __restrict__ rbf,
        const short* __restrict__ Wrh,
        const short* __restrict__ Wrl,
        const float* __restrict__ b_rbf,
        const float* __restrict__ xh,
        const float* __restrict__ vec,
        const int* __restrict__ perm,
        const int* __restrict__ dsts,
        const int* __restrict__ srcs,
        const float* __restrict__ evs,
        float* __restrict__ x1,
        float* __restrict__ vecacc) {
    int tid = threadIdx.x;
    int wave = tid >> 6, lane = tid & 63;
    int quad = lane >> 4, l16 = lane & 15;
    int bm = blockIdx.x * 128;
    int base = wave * 16;              // this wave's 16 rows

    __shared__ __align__(16) float mlds[128][66];
    __shared__ int dst_s[128], src_s[128];
    __shared__ float ev_s[128][3];

    if (lane < 16) {
        int i = base + lane;
        dst_s[i] = __builtin_nontemporal_load(dsts + bm + i);
        src_s[i] = __builtin_nontemporal_load(srcs + bm + i);
        ev_s[i][0] = __builtin_nontemporal_load(evs + (long)(bm + i) * 3 + 0);
        ev_s[i][1] = __builtin_nontemporal_load(evs + (long)(bm + i) * 3 + 1);
        ev_s[i][2] = __builtin_nontemporal_load(evs + (long)(bm + i) * 3 + 2);
    }

    int e0 = __builtin_nontemporal_load(perm + bm + base + l16);
    bf16x8 afh[2], afl[2];
    {
        long ebase = (long)e0 * 64 + quad * 8;
        #pragma unroll
        for (int ks = 0; ks < 2; ks++) {
            f32x4 ua = __builtin_nontemporal_load(
                reinterpret_cast<const f32x4*>(rbf + ebase + ks * 32));
            f32x4 ub = __builtin_nontemporal_load(
                reinterpret_cast<const f32x4*>(rbf + ebase + ks * 32 + 4));
            cvt8v(ua, ub, afh[ks], afl[ks]);
        }
    }

    // ---- sec0: m1 -> x1 (4 tiles) ----
    for (int tile = 0; tile < 4; tile++) {
        mfma_tile(tile * 64, base, quad, l16, afh, afl, Wrh, Wrl, b_rbf, mlds);
        int colx = tile * 64 + lane;
        float pv[16];
        #pragma unroll
        for (int i = 0; i < 16; i++) {
            long xb = (long)src_s[base + i] * 768;
            pv[i] = mlds[base + i][lane] * xh[xb + colx];
        }
        float a = 0.f;
        int dprev = dst_s[base];
        #pragma unroll
        for (int i = 0; i < 16; i++) {
            int d = dst_s[base + i];
            if (d != dprev) {
                atomicAdd(&x1[(long)dprev * 256 + colx], a);
                a = 0.f;
                dprev = d;
            }
            a += pv[i];
        }
        atomicAdd(&x1[(long)dprev * 256 + colx], a);
    }

    // ---- merged sec1+sec2: 3 atomics per run, no pm3 array ----
    for (int tile = 0; tile < 4; tile++) {
        int colx = tile * 64 + lane;
        // m2-tile -> pm2 (premultiplied by xh and constants)
        mfma_tile(256 + tile * 64, base, quad, l16, afh, afl, Wrh, Wrl, b_rbf, mlds);
        float pm2[16];
        #pragma unroll
        for (int i = 0; i < 16; i++) {
            long xb = (long)src_s[base + i] * 768;
            pm2[i] = mlds[base + i][lane] * (INV_SQRT_3f * INV_SQRT_Hf) *
                     xh[xb + 256 + colx];
        }
        // m3-tile overwrites this wave's mlds rows (same-wave in-order DS);
        // its product is computed inline in the batch loop below.
        mfma_tile(512 + tile * 64, base, quad, l16, afh, afl, Wrh, Wrl, b_rbf, mlds);

        float a0 = 0.f, a1 = 0.f, a2 = 0.f;
        int dprev = dst_s[base];
        #pragma unroll 1
        for (int b = 0; b < 4; b++) {
            float p0[4], p1[4], p2[4];
            #pragma unroll
            for (int j = 0; j < 4; j++) {
                int i = b * 4 + j;
                long xb = (long)src_s[base + i] * 768;
                float m3v = mlds[base + i][lane] * INV_SQRT_Hf * xh[xb + 512 + colx];
                p0[j] = vec[xb + colx] * pm2[i]       + ev_s[base + i][0] * m3v;
                p1[j] = vec[xb + 256 + colx] * pm2[i] + ev_s[base + i][1] * m3v;
                p2[j] = vec[xb + 512 + colx] * pm2[i] + ev_s[base + i][2] * m3v;
            }
            #pragma unroll
            for (int j = 0; j < 4; j++) {
                int i = b * 4 + j;
                int d = dst_s[base + i];
                if (d != dprev) {
                    long vb = (long)dprev * 768 + colx;
                    atomicAdd(&vecacc[vb], a0);
                    atomicAdd(&vecacc[vb + 256], a1);
                    atomicAdd(&vecacc[vb + 512], a2);
                    a0 = a1 = a2 = 0.f;
                    dprev = d;
                }
                a0 += p0[j]; a1 += p1[j]; a2 += p2[j];
            }
        }
        long vb = (long)dprev * 768 + colx;
        atomicAdd(&vecacc[vb], a0);
        atomicAdd(&vecacc[vb + 256], a1);
        atomicAdd(&vecacc[vb + 512], a2);
    }
}

// ---------------- vec_dot + vnorm + cat(x, vnorm) fp32 ----------------
__global__ void __launch_bounds__(256) vdot_cat_kernel(const float* __restrict__ vec1,
                                                       const short* __restrict__ vec2,
                                                       const float* __restrict__ x1,
                                                       float* __restrict__ vdot,
                                                       float* __restrict__ cat) {
    int idx = blockIdx.x * 256 + threadIdx.x;
    int n = idx >> 8, h = idx & 255;
    float dsum = 0.f, s2 = 0.f;
    #pragma unroll
    for (int d = 0; d < 3; d++) {
        long r = (long)(n * 3 + d) * 256 + h;
        float a = vec1[r];
        float b = b2f(vec2[r]);
        dsum += a * b;
        s2 += b * b;
    }
    vdot[idx] = dsum * INV_SQRT_Hf;
    cat[(long)n * 512 + h] = x1[idx];
    cat[(long)n * 512 + 256 + h] = sqrtf(s2 + 1e-8f);
}

// ---------------- x/vec update after xv MLP (IN-PLACE) ----------------
__global__ void __launch_bounds__(256) e4_kernel(float* __restrict__ x1,
                                                 float* __restrict__ vecacc,
                                                 const float* __restrict__ vec1,
                                                 const float* __restrict__ vdot,
                                                 const short* __restrict__ xvh_h,
                                                 const short* __restrict__ xvh_l) {
    int idx = blockIdx.x * 256 + threadIdx.x;
    int n = idx >> 8, h = idx & 255;
    long b0 = (long)n * 768 + h;
    float xv1 = b2f(xvh_h[b0])       + b2f(xvh_l[b0]);
    float xv2 = b2f(xvh_h[b0 + 256]) + b2f(xvh_l[b0 + 256]);
    float xv3 = b2f(xvh_h[b0 + 512]) + b2f(xvh_l[b0 + 512]);
    x1[idx] = x1[idx] + (xv1 + xv2 * vdot[idx]) * INV_SQRT_2f;
    #pragma unroll
    for (int d = 0; d < 3; d++) {
        long r = (long)(n * 3 + d) * 256 + h;
        vecacc[r] = vecacc[r] + xv3 * vec1[r];
    }
}

// ---------------- norm over d + concat(x fp32, norm) fp32 ----------------
__global__ void __launch_bounds__(256) normcat_kernel(const float* __restrict__ xin,
                                                      const short* __restrict__ w,
                                                      float* __restrict__ cat,
                                                      int Cx, int C, int shift) {
    int idx = blockIdx.x * 256 + threadIdx.x;
    int cols = 1 << shift;
    int n = idx >> shift, c = idx & (cols - 1);
    float v;
    if (c < Cx) {
        v = xin[(long)n * Cx + c];
    } else {
        int cc = c - Cx;
        float s = 0.f;
        #pragma unroll
        for (int d = 0; d < 3; d++) {
            float a = b2f(w[(long)(n * 3 + d) * C + cc]);
            s += a * a;
        }
        v = sqrtf(s);
    }
    cat[idx] = v;
}

// ---------------- gated block 1 epilogue (fp32 in/out) ----------------
__global__ void __launch_bounds__(256) gate1_kernel(const float* __restrict__ h1,
                                                    const float* __restrict__ w2,
                                                    float* __restrict__ x3,
                                                    float* __restrict__ vecC) {
    int idx = blockIdx.x * 256 + threadIdx.x;
    int n = idx >> 7, c = idx & 127;
    x3[idx] = ssilu_f(h1[(long)n * 256 + c]);
    float vn = h1[(long)n * 256 + 128 + c];
    #pragma unroll
    for (int d = 0; d < 3; d++) {
        long r = (long)(n * 3 + d) * 128 + c;
        vecC[r] = vn * w2[r];
    }
}

// ---------------- vecC @ o2_Wv2 (K=128, Nc=1): one wave per row ----------------
__global__ void __launch_bounds__(256) g12_kernel(const float* __restrict__ vecC,
                                                  const float* __restrict__ Wv2,
                                                  float* __restrict__ w4) {
    int row = blockIdx.x * 4 + (threadIdx.x >> 6);
    int lane = threadIdx.x & 63;
    long r0 = (long)row * 128 + lane;
    float s = vecC[r0] * Wv2[lane] + vecC[r0 + 64] * Wv2[64 + lane];
    #pragma unroll
    for (int off = 32; off > 0; off >>= 1) s += __shfl_down(s, off);
    if (lane == 0) w4[row] = s;
}

// ---------------- final: out[n,d] = (t5[n,:]@Wu2[:,1] + b2[1]) * w4[n,d] ----------
__global__ void __launch_bounds__(256) final_kernel(const float* __restrict__ t5,
                                                    const float* __restrict__ Wu2,
                                                    const float* __restrict__ bu2,
                                                    const float* __restrict__ w4,
                                                    float* __restrict__ out) {
    int n = blockIdx.x * 4 + (threadIdx.x >> 6);
    int lane = threadIdx.x & 63;
    float s = t5[(long)n * 128 + lane] * Wu2[lane * 2 + 1] +
              t5[(long)n * 128 + 64 + lane] * Wu2[(64 + lane) * 2 + 1];
    #pragma unroll
    for (int off = 32; off > 0; off >>= 1) s += __shfl_down(s, off);
    float val = __shfl(s, 0) + bu2[1];
    if (lane < 3) out[(long)n * 3 + lane] = val * w4[(long)n * 3 + lane];
}

extern "C" void kernel_launch(void* const* d_in, const int* in_sizes, int n_in,
                              void* d_out, int out_size, void* d_ws, size_t ws_size,
                              hipStream_t stream) {
    const float* x          = (const float*)d_in[0];
    const float* vec        = (const float*)d_in[1];
    const float* edge_rbf   = (const float*)d_in[2];
    const float* edge_vector= (const float*)d_in[3];
    const float* ln_g       = (const float*)d_in[4];
    const float* ln_b       = (const float*)d_in[5];
    const float* W_x1       = (const float*)d_in[6];
    const float* b_x1       = (const float*)d_in[7];
    const float* W_x2       = (const float*)d_in[8];
    const float* b_x2       = (const float*)d_in[9];
    const float* W_rbf      = (const float*)d_in[10];
    const float* b_rbf      = (const float*)d_in[11];
    const float* W_vp       = (const float*)d_in[12];
    const float* W_xv1      = (const float*)d_in[13];
    const float* b_xv1      = (const float*)d_in[14];
    const float* W_xv2      = (const float*)d_in[15];
    const float* b_xv2      = (const float*)d_in[16];
    const float* o1_Wv1     = (const float*)d_in[17];
    const float* o1_Wv2     = (const float*)d_in[18];
    const float* o1_Wu1     = (const float*)d_in[19];
    const float* o1_bu1     = (const float*)d_in[20];
    const float* o1_Wu2     = (const float*)d_in[21];
    const float* o1_bu2     = (const float*)d_in[22];
    const float* o2_Wv1     = (const float*)d_in[23];
    const float* o2_Wv2     = (const float*)d_in[24];
    const float* o2_Wu1     = (const float*)d_in[25];
    const float* o2_bu1     = (const float*)d_in[26];
    const float* o2_Wu2     = (const float*)d_in[27];
    const float* o2_bu2     = (const float*)d_in[28];
    const int*   edge_index = (const int*)d_in[29];
    float* out = (float*)d_out;
    float* ws  = (float*)d_ws;

    const size_t S = (size_t)NN * 256;
    const size_t Q = S / 4;              // 1,048,576 floats = 4 MiB
    // ---- arena in units of Q; peak 52Q = 208 MiB (proven safe) ----
    float* x1      = ws;                     // Q0-3   (fp32 S)
    float* vecacc  = ws + 4 * Q;             // Q4-15  (fp32 3S)
    short* wtb     = (short*)(ws + 16 * Q);  // Q16-17 weights hi + lo
    const long WLO = 1114112;
    // phase 1 (all fp32 now)
    float* xln   = ws + 18 * Q;              // Q18-21 (fp32 S, dead after t1 gemm)
    float* t1    = ws + 22 * Q;              // Q22-25 (fp32 S, dead after xh gemm)
    float* xh    = ws + 30 * Q;              // Q30-41 (fp32 3S, dead after gather)
    // phase 2 sort scratch (dead before vdot is written)
    int* rowptr    = (int*)(ws + 48 * Q);    // NN+1
    int* cursor    = rowptr + (NN + 1);      // NN
    int* perm      = cursor + NN;            // EE
    int* dsts      = perm + EE;              // EE
    int* srcs      = dsts + EE;              // EE
    float* evs     = (float*)(srcs + EE);    // 3*EE
    // phase 3
    float* vec1  = ws + 30 * Q;              // Q30-41 (fp32 3S, live till e4)
    short* vec2b = (short*)(ws + 42 * Q);    // Q42-47 (bf16 3S)
    float* vdot  = ws + 48 * Q;              // Q48-51 (fp32 S, live till e4)
    float* cat   = ws + 18 * Q;              // Q18-25 (fp32 2S; xln/t1 dead)
    float* t2    = ws + 26 * Q;              // Q26-29 (fp32 S)
    short* xvh_h = (short*)(ws + 18 * Q);    // Q18-23 (cat dead after xv1 gemm)
    short* xvh_l = (short*)(ws + 42 * Q);    // Q42-47 (vec2b dead after vdot_cat)
    // phase 4
    short* w1b   = (short*)(ws + 30 * Q);    // Q30-35 (bf16 3S; vec1 dead after e4)
    float* w2    = ws + 36 * Q;              // Q36-41 (fp32 3*NN*128)
    float* cat2  = ws + 42 * Q;              // Q42-49 (fp32 2S; xvh_l/vdot dead)
    float* t4    = ws + 18 * Q;              // Q18-21 (fp32 S; xvh_h dead)
    float* h1    = ws + 22 * Q;              // Q22-25 (fp32 S)
    float* x3    = ws + 26 * Q;              // Q26-27 (fp32 S/2)
    float* vecC  = ws + 28 * Q;              // Q28-33 (fp32 3*NN*128)
    // phase 5
    short* w3b   = (short*)(ws + 34 * Q);    // Q34-36 (bf16 3*NN*128)
    float* w4    = ws + 37 * Q;              // Q37
    float* cat3  = ws + 38 * Q;              // Q38-41 (fp32 NN*256)
    float* t5    = ws + 42 * Q;              // Q42-43

    // weight hi/lo offsets (shorts)
    short* WT_x1    = wtb;
    short* WT_x2    = wtb + 65536;
    short* WT_vp    = wtb + 262144;          // [n<512][k<256] contiguous -> fused vp
    short* WT_xv1   = wtb + 393216;
    short* WT_xv2   = wtb + 524288;
    short* WT_o1Wv1 = wtb + 720896;          // [n<256][k<256]; o1Wv2 follows -> fused N=384
    short* WT_o1Wv2 = wtb + 786432;
    short* WT_o1Wu1 = wtb + 819200;
    short* WT_o1Wu2 = wtb + 950272;
    short* WT_o2Wv1 = wtb + 1015808;
    short* WT_o2Wu1 = wtb + 1032192;
    short* WT_rbf   = wtb + 1064960;         // 768 x 64

    // Phase 0: all weight transposes + splits in one launch (incl. W_rbf^T)
    WtArgs wa;
    const float* wsrc[12] = {W_x1, W_x2, W_vp, W_xv1, W_xv2, o1_Wv1, o1_Wv2,
                             o1_Wu1, o1_Wu2, o2_Wv1, o2_Wu1, W_rbf};
    int wk[12] = {256, 256, 256, 512, 256, 256, 256, 512, 256, 128, 256, 64};
    int wn[12] = {256, 768, 512, 256, 768, 256, 128, 256, 256, 128, 128, 768};
    int off = 0;
    for (int i = 0; i < 12; i++) {
        wa.W[i] = wsrc[i]; wa.K[i] = wk[i]; wa.N[i] = wn[i];
        wa.off[i] = off; off += wk[i] * wn[i];
    }
    wa.off[12] = off;  // 1,114,112
    wt_split_all<<<off / 256, 256, 0, stream>>>(wa, wtb, wtb + WLO);

    // Phase 1: node MLP (+ x1/vecacc init; memcpy folded into ln_kernel)
    ln_kernel<<<NN, 256, 0, stream>>>(x, vec, ln_g, ln_b, xln, x1, vecacc);
    mfma_gemm<<<dim3(NN / 128, 4), 256, 0, stream>>>(xln, WT_x1, WT_x1 + WLO,
                                                     b_x1, t1, nullptr, NN, 256, 256, 1);
    mfma_gemm<<<dim3(NN / 128, 12), 256, 0, stream>>>(t1, WT_x2, WT_x2 + WLO,
                                                      b_x2, xh, nullptr, NN, 256, 768, 0);

    // Phase 2: sort edges by dst; edge-parallel fused gather (atomics)
    zero_kernel<<<(NN + 255) / 256, 256, 0, stream>>>(cursor, NN);
    hist_kernel<<<EE / 256, 256, 0, stream>>>(edge_index, cursor);
    scan_kernel<<<1, 256, 0, stream>>>(cursor, rowptr);
    scatter_kernel<<<EE / 256, 256, 0, stream>>>(edge_index, edge_vector, cursor,
                                                 perm, dsts, srcs, evs);
    edge_gather_kernel<<<EE / 128, 512, 0, stream>>>(
        edge_rbf, WT_rbf, WT_rbf + WLO, b_rbf, xh, vec,
        perm, dsts, srcs, evs, x1, vecacc);

    // Phase 3: fused vp (N=512: cols<256 -> fp32 vec1, >=256 -> bf16 vec2b)
    mfma_gemm<<<dim3(3 * NN / 128, 8), 256, 0, stream>>>(vecacc, WT_vp, WT_vp + WLO,
                                                         nullptr, vec1, vec2b,
                                                         3 * NN, 256, 512, 4);
    vdot_cat_kernel<<<NN, 256, 0, stream>>>(vec1, vec2b, x1, vdot, cat);
    mfma_gemm<<<dim3(NN / 128, 4), 256, 0, stream>>>(cat, WT_xv1, WT_xv1 + WLO,
                                                     b_xv1, t2, nullptr, NN, 512, 256, 1);
    mfma_gemm<<<dim3(NN / 128, 12), 256, 0, stream>>>(t2, WT_xv2, WT_xv2 + WLO,
                                                      b_xv2, xvh_h, xvh_l, NN, 256, 768, 3);
    e4_kernel<<<NN, 256, 0, stream>>>(x1, vecacc, vec1, vdot, xvh_h, xvh_l);

    // Phase 4: fused o1Wv (N=384: cols<256 -> bf16 w1b, >=256 -> fp32 w2)
    mfma_gemm<<<dim3(3 * NN / 128, 6), 256, 0, stream>>>(vecacc, WT_o1Wv1, WT_o1Wv1 + WLO,
                                                         nullptr, w1b, w2,
                                                         3 * NN, 256, 384, 5);
    normcat_kernel<<<NN * 512 / 256, 256, 0, stream>>>(x1, w1b, cat2, 256, 256, 9);
    mfma_gemm<<<dim3(NN / 128, 4), 256, 0, stream>>>(cat2, WT_o1Wu1, WT_o1Wu1 + WLO,
                                                     o1_bu1, t4, nullptr, NN, 512, 256, 1);
    mfma_gemm<<<dim3(NN / 128, 4), 256, 0, stream>>>(t4, WT_o1Wu2, WT_o1Wu2 + WLO,
                                                     o1_bu2, h1, nullptr, NN, 256, 256, 0);
    gate1_kernel<<<NN * 128 / 256, 256, 0, stream>>>(h1, w2, x3, vecC);

    // Phase 5: gated equivariant block 2 + output
    mfma_gemm<<<dim3(3 * NN / 128, 2), 256, 0, stream>>>(vecC, WT_o2Wv1, WT_o2Wv1 + WLO,
                                                         nullptr, w3b, nullptr,
                                                         3 * NN, 128, 128, 2);
    g12_kernel<<<3 * NN / 4, 256, 0, stream>>>(vecC, o2_Wv2, w4);
    normcat_kernel<<<NN * 256 / 256, 256, 0, stream>>>(x3, w3b, cat3, 128, 128, 8);
    mfma_gemm<<<dim3(NN / 128, 2), 256, 0, stream>>>(cat3, WT_o2Wu1, WT_o2Wu1 + WLO,
                                                     o2_bu1, t5, nullptr, NN, 256, 128, 1);
    final_kernel<<<NN / 4, 256, 0, stream>>>(t5, o2_Wu2, o2_bu2, w4, out);
}

// Round 13
// 1426.910 us; speedup vs baseline: 1.6719x; 1.6719x over previous
//
#include <hip/hip_runtime.h>
#include <math.h>

#define NN 16384
#define EE 262144
#define HH 256

#define INV_SQRT_3f 0.57735026918962576f
#define INV_SQRT_Hf 0.0625f
#define INV_SQRT_2f 0.70710678118654752f
#define SSILU_SCALE 1.6666666666666667f

typedef __attribute__((ext_vector_type(8))) short bf16x8;
typedef __attribute__((ext_vector_type(4))) float f32x4;

__device__ __forceinline__ float ssilu_f(float v) {
    return v * (1.0f / (1.0f + __expf(-v))) * SSILU_SCALE;
}
__device__ __forceinline__ float b2f(short s) {
    unsigned int u = ((unsigned int)(unsigned short)s) << 16;
    return __uint_as_float(u);
}
__device__ __forceinline__ short f2b(float f) {
    unsigned int u = __float_as_uint(f);
    unsigned int r = (u + 0x7fff + ((u >> 16) & 1)) >> 16;
    return (short)r;
}
// fp32x8 -> split hi/lo bf16x8 in registers (same rounding as the old split4)
__device__ __forceinline__ void cvt8(float4 a, float4 b, bf16x8& h, bf16x8& l) {
    float v[8] = {a.x, a.y, a.z, a.w, b.x, b.y, b.z, b.w};
    #pragma unroll
    for (int j = 0; j < 8; j++) {
        short hh = f2b(v[j]);
        h[j] = hh;
        l[j] = f2b(v[j] - b2f(hh));
    }
}
// same, from native ext-vector f32x4 (usable with __builtin_nontemporal_load)
__device__ __forceinline__ void cvt8v(f32x4 a, f32x4 b, bf16x8& h, bf16x8& l) {
    float v[8] = {a.x, a.y, a.z, a.w, b.x, b.y, b.z, b.w};
    #pragma unroll
    for (int j = 0; j < 8; j++) {
        short hh = f2b(v[j]);
        h[j] = hh;
        l[j] = f2b(v[j] - b2f(hh));
    }
}

// ---------------- LayerNorm: one block per row, fp32 out + x1/vecacc init ------
__global__ void __launch_bounds__(256) ln_kernel(const float* __restrict__ x,
                                                 const float* __restrict__ vec,
                                                 const float* __restrict__ g,
                                                 const float* __restrict__ b,
                                                 float* __restrict__ o_,
                                                 float* __restrict__ x1,
                                                 float* __restrict__ vecacc) {
    int n = blockIdx.x;
    int t = threadIdx.x;
    float v = x[(long)n * HH + t];
    x1[(long)n * HH + t] = v;
    long vb = (long)n * 768 + t;
    vecacc[vb]       = vec[vb];
    vecacc[vb + 256] = vec[vb + 256];
    vecacc[vb + 512] = vec[vb + 512];
    float s = v, s2 = v * v;
    #pragma unroll
    for (int off = 32; off > 0; off >>= 1) {
        s  += __shfl_down(s, off);
        s2 += __shfl_down(s2, off);
    }
    __shared__ float red[8];
    int wave = t >> 6, lane = t & 63;
    if (lane == 0) { red[wave] = s; red[4 + wave] = s2; }
    __syncthreads();
    __shared__ float mr[2];
    if (t == 0) {
        float ts = red[0] + red[1] + red[2] + red[3];
        float ts2 = red[4] + red[5] + red[6] + red[7];
        float mean = ts * (1.0f / HH);
        float var = ts2 * (1.0f / HH) - mean * mean;
        mr[0] = mean;
        mr[1] = rsqrtf(var + 1e-5f);
    }
    __syncthreads();
    o_[(long)n * HH + t] = (v - mr[0]) * mr[1] * g[t] + b[t];
}

// ---- ALL weight transposes + hi/lo splits in ONE kernel (incl. W_rbf) ----
struct WtArgs {
    const float* W[12];
    int K[12];
    int N[12];
    int off[13];   // cumulative element offsets; off[12] = total
};

__global__ void __launch_bounds__(256) wt_split_all(WtArgs a,
                                                    short* __restrict__ WTh,
                                                    short* __restrict__ WTl) {
    int idx = blockIdx.x * 256 + threadIdx.x;
    int s = 0;
    #pragma unroll
    for (int i = 1; i < 12; i++) s += (idx >= a.off[i]) ? 1 : 0;
    int local = idx - a.off[s];
    int K = a.K[s], N = a.N[s];
    int k = local / N, n = local - k * N;
    float w = a.W[s][local];
    short hh = f2b(w);
    long o = (long)a.off[s] + (long)n * K + k;
    WTh[o] = hh;
    WTl[o] = f2b(w - b2f(hh));
}

// ---- split-bf16 MFMA GEMM v3: fp32 A, in-register hi/lo split ----
// act 0: fp32 out C1          act 1: ssilu + fp32 out C1
// act 2: bf16 out C1          act 3: split out (C1 hi, C2 lo)
// act 4: col<256 -> fp32 C1[row*256+col]; col>=256 -> bf16 C2[row*256+col-256]
// act 5: col<256 -> bf16 C1[row*256+col]; col>=256 -> fp32 C2[row*128+col-256]
__global__ void __launch_bounds__(256) mfma_gemm(const float* __restrict__ A,
                                                 const short* __restrict__ Wh,
                                                 const short* __restrict__ Wl,
                                                 const float* __restrict__ bias,
                                                 void* __restrict__ C1,
                                                 void* __restrict__ C2,
                                                 int M, int K, int N, int act) {
    int tid = threadIdx.x;
    int wave = tid >> 6, lane = tid & 63;
    int quad = lane >> 4, l16 = lane & 15;
    long bm = (long)blockIdx.x * 128 + wave * 32;
    long bn = (long)blockIdx.y * 64;
    long a0 = (bm + l16) * K + quad * 8;
    long a1 = a0 + (long)16 * K;
    long w0 = (bn + l16) * K + quad * 8;

    f32x4 acc[2][4];
    #pragma unroll
    for (int f = 0; f < 2; f++)
        #pragma unroll
        for (int t = 0; t < 4; t++) acc[f][t] = (f32x4){0.f, 0.f, 0.f, 0.f};

    bf16x8 cah[2], cal[2], cbh[4], cbl[4];
    cvt8(*(const float4*)(A + a0), *(const float4*)(A + a0 + 4), cah[0], cal[0]);
    cvt8(*(const float4*)(A + a1), *(const float4*)(A + a1 + 4), cah[1], cal[1]);
    #pragma unroll
    for (int t = 0; t < 4; t++) {
        long wo = w0 + (long)t * 16 * K;
        cbh[t] = *(const bf16x8*)(Wh + wo);
        cbl[t] = *(const bf16x8*)(Wl + wo);
    }

    for (int k0 = 0; k0 < K; k0 += 32) {
        int k1 = k0 + 32;
        float4 n0a, n0b, n1a, n1b;
        bf16x8 nbh[4], nbl[4];
        if (k1 < K) {
            n0a = *(const float4*)(A + a0 + k1);
            n0b = *(const float4*)(A + a0 + k1 + 4);
            n1a = *(const float4*)(A + a1 + k1);
            n1b = *(const float4*)(A + a1 + k1 + 4);
            #pragma unroll
            for (int t = 0; t < 4; t++) {
                long wo = w0 + (long)t * 16 * K + k1;
                nbh[t] = *(const bf16x8*)(Wh + wo);
                nbl[t] = *(const bf16x8*)(Wl + wo);
            }
        }
        #pragma unroll
        for (int t = 0; t < 4; t++) {
            #pragma unroll
            for (int f = 0; f < 2; f++) {
                acc[f][t] = __builtin_amdgcn_mfma_f32_16x16x32_bf16(cah[f], cbh[t], acc[f][t], 0, 0, 0);
                acc[f][t] = __builtin_amdgcn_mfma_f32_16x16x32_bf16(cal[f], cbh[t], acc[f][t], 0, 0, 0);
                acc[f][t] = __builtin_amdgcn_mfma_f32_16x16x32_bf16(cah[f], cbl[t], acc[f][t], 0, 0, 0);
            }
        }
        if (k1 < K) {
            cvt8(n0a, n0b, cah[0], cal[0]);
            cvt8(n1a, n1b, cah[1], cal[1]);
            #pragma unroll
            for (int t = 0; t < 4; t++) { cbh[t] = nbh[t]; cbl[t] = nbl[t]; }
        }
    }

    #pragma unroll
    for (int f = 0; f < 2; f++) {
        long row0 = bm + f * 16 + quad * 4;
        #pragma unroll
        for (int t = 0; t < 4; t++) {
            long col = bn + t * 16 + l16;
            float bv = bias ? bias[col] : 0.f;
            #pragma unroll
            for (int r = 0; r < 4; r++) {
                float v = acc[f][t][r] + bv;
                long row = row0 + r;
                if (act == 4) {
                    if (col < 256) ((float*)C1)[row * 256 + col] = v;
                    else           ((short*)C2)[row * 256 + col - 256] = f2b(v);
                } else if (act == 5) {
                    if (col < 256) ((short*)C1)[row * 256 + col] = f2b(v);
                    else           ((float*)C2)[row * 128 + col - 256] = v;
                } else {
                    long idx = row * N + col;
                    if (act == 3) {
                        short hh = f2b(v);
                        ((short*)C1)[idx] = hh;
                        ((short*)C2)[idx] = f2b(v - b2f(hh));
                    } else if (act == 2) {
                        ((short*)C1)[idx] = f2b(v);
                    } else {
                        if (act == 1) v = ssilu_f(v);
                        ((float*)C1)[idx] = v;
                    }
                }
            }
        }
    }
}

// ---------------- edge sort (counting sort by dst) ----------------
__global__ void __launch_bounds__(256) zero_kernel(int* __restrict__ p, int n) {
    int i = blockIdx.x * 256 + threadIdx.x;
    if (i < n) p[i] = 0;
}

__global__ void __launch_bounds__(256) hist_kernel(const int* __restrict__ eidx,
                                                   int* __restrict__ cnt) {
    int e = blockIdx.x * 256 + threadIdx.x;
    atomicAdd(&cnt[eidx[EE + e]], 1);
}

__global__ void __launch_bounds__(256) scan_kernel(int* __restrict__ cursor,
                                                   int* __restrict__ rowptr) {
    int t = threadIdx.x;
    int base_i = t * 64;
    int tsum = 0;
    for (int i = 0; i < 64; i++) tsum += cursor[base_i + i];
    __shared__ int ls[256];
    ls[t] = tsum;
    __syncthreads();
    for (int off = 1; off < 256; off <<= 1) {
        int v = (t >= off) ? ls[t - off] : 0;
        __syncthreads();
        ls[t] += v;
        __syncthreads();
    }
    int running = ls[t] - tsum;
    for (int i = 0; i < 64; i++) {
        int c = cursor[base_i + i];
        rowptr[base_i + i] = running;
        cursor[base_i + i] = running;
        running += c;
    }
    if (t == 255) rowptr[NN] = running;
}

// scatter: also materialize dst/src/ev in sorted order for the edge kernel
__global__ void __launch_bounds__(256) scatter_kernel(const int* __restrict__ eidx,
                                                      const float* __restrict__ ev,
                                                      int* __restrict__ cursor,
                                                      int* __restrict__ perm,
                                                      int* __restrict__ dsts,
                                                      int* __restrict__ srcs,
                                                      float* __restrict__ evs) {
    int e = blockIdx.x * 256 + threadIdx.x;
    int s_ = eidx[e];
    int d_ = eidx[EE + e];
    int pos = atomicAdd(&cursor[d_], 1);
    perm[pos] = e;
    dsts[pos] = d_;
    srcs[pos] = s_;
    evs[pos * 3 + 0] = ev[e * 3 + 0];
    evs[pos * 3 + 1] = ev[e * 3 + 1];
    evs[pos * 3 + 2] = ev[e * 3 + 2];
}

// ---------------- Edge-parallel fused rbf-GEMM + gather + atomic reduce -------
// v9 == round-10's proven best (454 us): 8 waves x 16 edges, barrier-free,
// nt-loads on streams, separate sec0/sec1/sec2 consume with batched MLP,
// natural register allocation (48 VGPR, no min-wave pin). The atomic-merge
// variants (R11: 68 VGPR occupancy cliff; R12: pinned -> scratch spill,
// 3.6 GB HBM) are conclusively worse — reverted.
__global__ void __launch_bounds__(512) edge_gather_kernel(
        const float* __restrict__ rbf,
        const short* __restrict__ Wrh,
        const short* __restrict__ Wrl,
        const float* __restrict__ b_rbf,
        const float* __restrict__ xh,
        const float* __restrict__ vec,
        const int* __restrict__ perm,
        const int* __restrict__ dsts,
        const int* __restrict__ srcs,
        const float* __restrict__ evs,
        float* __restrict__ x1,
        float* __restrict__ vecacc) {
    int tid = threadIdx.x;
    int wave = tid >> 6, lane = tid & 63;
    int quad = lane >> 4, l16 = lane & 15;
    int bm = blockIdx.x * 128;
    int base = wave * 16;              // this wave's 16 rows

    __shared__ __align__(16) float mlds[128][66];
    __shared__ int dst_s[128], src_s[128];
    __shared__ float ev_s[128][3];

    if (lane < 16) {
        int i = base + lane;
        dst_s[i] = __builtin_nontemporal_load(dsts + bm + i);
        src_s[i] = __builtin_nontemporal_load(srcs + bm + i);
        ev_s[i][0] = __builtin_nontemporal_load(evs + (long)(bm + i) * 3 + 0);
        ev_s[i][1] = __builtin_nontemporal_load(evs + (long)(bm + i) * 3 + 1);
        ev_s[i][2] = __builtin_nontemporal_load(evs + (long)(bm + i) * 3 + 2);
    }

    int e0 = __builtin_nontemporal_load(perm + bm + base + l16);
    bf16x8 afh[2], afl[2];
    {
        long ebase = (long)e0 * 64 + quad * 8;
        #pragma unroll
        for (int ks = 0; ks < 2; ks++) {
            f32x4 ua = __builtin_nontemporal_load(
                reinterpret_cast<const f32x4*>(rbf + ebase + ks * 32));
            f32x4 ub = __builtin_nontemporal_load(
                reinterpret_cast<const f32x4*>(rbf + ebase + ks * 32 + 4));
            cvt8v(ua, ub, afh[ks], afl[ks]);
        }
    }

    for (int sec = 0; sec < 3; sec++) {
        for (int tile = 0; tile < 4; tile++) {
            int bn = sec * 256 + tile * 64;
            f32x4 acc[4];
            #pragma unroll
            for (int t = 0; t < 4; t++) {
                float bv = b_rbf[bn + t * 16 + l16];
                acc[t] = (f32x4){bv, bv, bv, bv};
                #pragma unroll
                for (int ks = 0; ks < 2; ks++) {
                    long wo = (long)(bn + t * 16 + l16) * 64 + ks * 32 + quad * 8;
                    bf16x8 bh = *(const bf16x8*)(Wrh + wo);
                    bf16x8 bl = *(const bf16x8*)(Wrl + wo);
                    acc[t] = __builtin_amdgcn_mfma_f32_16x16x32_bf16(afh[ks], bh, acc[t], 0, 0, 0);
                    acc[t] = __builtin_amdgcn_mfma_f32_16x16x32_bf16(afl[ks], bh, acc[t], 0, 0, 0);
                    acc[t] = __builtin_amdgcn_mfma_f32_16x16x32_bf16(afh[ks], bl, acc[t], 0, 0, 0);
                }
            }
            #pragma unroll
            for (int t = 0; t < 4; t++)
                #pragma unroll
                for (int r = 0; r < 4; r++)
                    mlds[base + quad * 4 + r][t * 16 + l16] = acc[t][r];

            int colx = tile * 64 + lane;
            if (sec == 0) {
                float pv[16];
                #pragma unroll
                for (int i = 0; i < 16; i++) {
                    long xb = (long)src_s[base + i] * 768;
                    pv[i] = mlds[base + i][lane] * xh[xb + colx];
                }
                float a = 0.f;
                int dprev = dst_s[base];
                #pragma unroll
                for (int i = 0; i < 16; i++) {
                    int d = dst_s[base + i];
                    if (d != dprev) {
                        atomicAdd(&x1[(long)dprev * 256 + colx], a);
                        a = 0.f;
                        dprev = d;
                    }
                    a += pv[i];
                }
                atomicAdd(&x1[(long)dprev * 256 + colx], a);
            } else if (sec == 1) {
                float a0 = 0.f, a1 = 0.f, a2 = 0.f;
                int dprev = dst_s[base];
                #pragma unroll 1
                for (int b = 0; b < 4; b++) {
                    float p0[4], p1[4], p2[4];
                    #pragma unroll
                    for (int j = 0; j < 4; j++) {
                        int i = b * 4 + j;
                        long xb = (long)src_s[base + i] * 768;
                        float m2 = mlds[base + i][lane] * (INV_SQRT_3f * INV_SQRT_Hf) *
                                   xh[xb + 256 + colx];
                        p0[j] = vec[xb + colx] * m2;
                        p1[j] = vec[xb + 256 + colx] * m2;
                        p2[j] = vec[xb + 512 + colx] * m2;
                    }
                    #pragma unroll
                    for (int j = 0; j < 4; j++) {
                        int i = b * 4 + j;
                        int d = dst_s[base + i];
                        if (d != dprev) {
                            long vb = (long)dprev * 768 + colx;
                            atomicAdd(&vecacc[vb], a0);
                            atomicAdd(&vecacc[vb + 256], a1);
                            atomicAdd(&vecacc[vb + 512], a2);
                            a0 = a1 = a2 = 0.f;
                            dprev = d;
                        }
                        a0 += p0[j]; a1 += p1[j]; a2 += p2[j];
                    }
                }
                long vb = (long)dprev * 768 + colx;
                atomicAdd(&vecacc[vb], a0);
                atomicAdd(&vecacc[vb + 256], a1);
                atomicAdd(&vecacc[vb + 512], a2);
            } else {
                float pm[16];
                #pragma unroll
                for (int i = 0; i < 16; i++) {
                    long xb = (long)src_s[base + i] * 768;
                    pm[i] = mlds[base + i][lane] * INV_SQRT_Hf * xh[xb + 512 + colx];
                }
                float a0 = 0.f, a1 = 0.f, a2 = 0.f;
                int dprev = dst_s[base];
                #pragma unroll
                for (int i = 0; i < 16; i++) {
                    int d = dst_s[base + i];
                    if (d != dprev) {
                        long vb = (long)dprev * 768 + colx;
                        atomicAdd(&vecacc[vb], a0);
                        atomicAdd(&vecacc[vb + 256], a1);
                        atomicAdd(&vecacc[vb + 512], a2);
                        a0 = a1 = a2 = 0.f;
                        dprev = d;
                    }
                    a0 += pm[i] * ev_s[base + i][0];
                    a1 += pm[i] * ev_s[base + i][1];
                    a2 += pm[i] * ev_s[base + i][2];
                }
                long vb = (long)dprev * 768 + colx;
                atomicAdd(&vecacc[vb], a0);
                atomicAdd(&vecacc[vb + 256], a1);
                atomicAdd(&vecacc[vb + 512], a2);
            }
        }
    }
}

// ---------------- vec_dot + vnorm + cat(x, vnorm) fp32 ----------------
__global__ void __launch_bounds__(256) vdot_cat_kernel(const float* __restrict__ vec1,
                                                       const short* __restrict__ vec2,
                                                       const float* __restrict__ x1,
                                                       float* __restrict__ vdot,
                                                       float* __restrict__ cat) {
    int idx = blockIdx.x * 256 + threadIdx.x;
    int n = idx >> 8, h = idx & 255;
    float dsum = 0.f, s2 = 0.f;
    #pragma unroll
    for (int d = 0; d < 3; d++) {
        long r = (long)(n * 3 + d) * 256 + h;
        float a = vec1[r];
        float b = b2f(vec2[r]);
        dsum += a * b;
        s2 += b * b;
    }
    vdot[idx] = dsum * INV_SQRT_Hf;
    cat[(long)n * 512 + h] = x1[idx];
    cat[(long)n * 512 + 256 + h] = sqrtf(s2 + 1e-8f);
}

// ---------------- x/vec update after xv MLP (IN-PLACE) ----------------
__global__ void __launch_bounds__(256) e4_kernel(float* __restrict__ x1,
                                                 float* __restrict__ vecacc,
                                                 const float* __restrict__ vec1,
                                                 const float* __restrict__ vdot,
                                                 const short* __restrict__ xvh_h,
                                                 const short* __restrict__ xvh_l) {
    int idx = blockIdx.x * 256 + threadIdx.x;
    int n = idx >> 8, h = idx & 255;
    long b0 = (long)n * 768 + h;
    float xv1 = b2f(xvh_h[b0])       + b2f(xvh_l[b0]);
    float xv2 = b2f(xvh_h[b0 + 256]) + b2f(xvh_l[b0 + 256]);
    float xv3 = b2f(xvh_h[b0 + 512]) + b2f(xvh_l[b0 + 512]);
    x1[idx] = x1[idx] + (xv1 + xv2 * vdot[idx]) * INV_SQRT_2f;
    #pragma unroll
    for (int d = 0; d < 3; d++) {
        long r = (long)(n * 3 + d) * 256 + h;
        vecacc[r] = vecacc[r] + xv3 * vec1[r];
    }
}

// ---------------- norm over d + concat(x fp32, norm) fp32 ----------------
__global__ void __launch_bounds__(256) normcat_kernel(const float* __restrict__ xin,
                                                      const short* __restrict__ w,
                                                      float* __restrict__ cat,
                                                      int Cx, int C, int shift) {
    int idx = blockIdx.x * 256 + threadIdx.x;
    int cols = 1 << shift;
    int n = idx >> shift, c = idx & (cols - 1);
    float v;
    if (c < Cx) {
        v = xin[(long)n * Cx + c];
    } else {
        int cc = c - Cx;
        float s = 0.f;
        #pragma unroll
        for (int d = 0; d < 3; d++) {
            float a = b2f(w[(long)(n * 3 + d) * C + cc]);
            s += a * a;
        }
        v = sqrtf(s);
    }
    cat[idx] = v;
}

// ---------------- gated block 1 epilogue (fp32 in/out) ----------------
__global__ void __launch_bounds__(256) gate1_kernel(const float* __restrict__ h1,
                                                    const float* __restrict__ w2,
                                                    float* __restrict__ x3,
                                                    float* __restrict__ vecC) {
    int idx = blockIdx.x * 256 + threadIdx.x;
    int n = idx >> 7, c = idx & 127;
    x3[idx] = ssilu_f(h1[(long)n * 256 + c]);
    float vn = h1[(long)n * 256 + 128 + c];
    #pragma unroll
    for (int d = 0; d < 3; d++) {
        long r = (long)(n * 3 + d) * 128 + c;
        vecC[r] = vn * w2[r];
    }
}

// ---------------- vecC @ o2_Wv2 (K=128, Nc=1): one wave per row ----------------
__global__ void __launch_bounds__(256) g12_kernel(const float* __restrict__ vecC,
                                                  const float* __restrict__ Wv2,
                                                  float* __restrict__ w4) {
    int row = blockIdx.x * 4 + (threadIdx.x >> 6);
    int lane = threadIdx.x & 63;
    long r0 = (long)row * 128 + lane;
    float s = vecC[r0] * Wv2[lane] + vecC[r0 + 64] * Wv2[64 + lane];
    #pragma unroll
    for (int off = 32; off > 0; off >>= 1) s += __shfl_down(s, off);
    if (lane == 0) w4[row] = s;
}

// ---------------- final: out[n,d] = (t5[n,:]@Wu2[:,1] + b2[1]) * w4[n,d] ----------
__global__ void __launch_bounds__(256) final_kernel(const float* __restrict__ t5,
                                                    const float* __restrict__ Wu2,
                                                    const float* __restrict__ bu2,
                                                    const float* __restrict__ w4,
                                                    float* __restrict__ out) {
    int n = blockIdx.x * 4 + (threadIdx.x >> 6);
    int lane = threadIdx.x & 63;
    float s = t5[(long)n * 128 + lane] * Wu2[lane * 2 + 1] +
              t5[(long)n * 128 + 64 + lane] * Wu2[(64 + lane) * 2 + 1];
    #pragma unroll
    for (int off = 32; off > 0; off >>= 1) s += __shfl_down(s, off);
    float val = __shfl(s, 0) + bu2[1];
    if (lane < 3) out[(long)n * 3 + lane] = val * w4[(long)n * 3 + lane];
}

extern "C" void kernel_launch(void* const* d_in, const int* in_sizes, int n_in,
                              void* d_out, int out_size, void* d_ws, size_t ws_size,
                              hipStream_t stream) {
    const float* x          = (const float*)d_in[0];
    const float* vec        = (const float*)d_in[1];
    const float* edge_rbf   = (const float*)d_in[2];
    const float* edge_vector= (const float*)d_in[3];
    const float* ln_g       = (const float*)d_in[4];
    const float* ln_b       = (const float*)d_in[5];
    const float* W_x1       = (const float*)d_in[6];
    const float* b_x1       = (const float*)d_in[7];
    const float* W_x2       = (const float*)d_in[8];
    const float* b_x2       = (const float*)d_in[9];
    const float* W_rbf      = (const float*)d_in[10];
    const float* b_rbf      = (const float*)d_in[11];
    const float* W_vp       = (const float*)d_in[12];
    const float* W_xv1      = (const float*)d_in[13];
    const float* b_xv1      = (const float*)d_in[14];
    const float* W_xv2      = (const float*)d_in[15];
    const float* b_xv2      = (const float*)d_in[16];
    const float* o1_Wv1     = (const float*)d_in[17];
    const float* o1_Wv2     = (const float*)d_in[18];
    const float* o1_Wu1     = (const float*)d_in[19];
    const float* o1_bu1     = (const float*)d_in[20];
    const float* o1_Wu2     = (const float*)d_in[21];
    const float* o1_bu2     = (const float*)d_in[22];
    const float* o2_Wv1     = (const float*)d_in[23];
    const float* o2_Wv2     = (const float*)d_in[24];
    const float* o2_Wu1     = (const float*)d_in[25];
    const float* o2_bu1     = (const float*)d_in[26];
    const float* o2_Wu2     = (const float*)d_in[27];
    const float* o2_bu2     = (const float*)d_in[28];
    const int*   edge_index = (const int*)d_in[29];
    float* out = (float*)d_out;
    float* ws  = (float*)d_ws;

    const size_t S = (size_t)NN * 256;
    const size_t Q = S / 4;              // 1,048,576 floats = 4 MiB
    // ---- arena in units of Q; peak 52Q = 208 MiB (proven safe) ----
    float* x1      = ws;                     // Q0-3   (fp32 S)
    float* vecacc  = ws + 4 * Q;             // Q4-15  (fp32 3S)
    short* wtb     = (short*)(ws + 16 * Q);  // Q16-17 weights hi + lo
    const long WLO = 1114112;
    // phase 1 (all fp32 now)
    float* xln   = ws + 18 * Q;              // Q18-21 (fp32 S, dead after t1 gemm)
    float* t1    = ws + 22 * Q;              // Q22-25 (fp32 S, dead after xh gemm)
    float* xh    = ws + 30 * Q;              // Q30-41 (fp32 3S, dead after gather)
    // phase 2 sort scratch (dead before vdot is written)
    int* rowptr    = (int*)(ws + 48 * Q);    // NN+1
    int* cursor    = rowptr + (NN + 1);      // NN
    int* perm      = cursor + NN;            // EE
    int* dsts      = perm + EE;              // EE
    int* srcs      = dsts + EE;              // EE
    float* evs     = (float*)(srcs + EE);    // 3*EE
    // phase 3
    float* vec1  = ws + 30 * Q;              // Q30-41 (fp32 3S, live till e4)
    short* vec2b = (short*)(ws + 42 * Q);    // Q42-47 (bf16 3S)
    float* vdot  = ws + 48 * Q;              // Q48-51 (fp32 S, live till e4)
    float* cat   = ws + 18 * Q;              // Q18-25 (fp32 2S; xln/t1 dead)
    float* t2    = ws + 26 * Q;              // Q26-29 (fp32 S)
    short* xvh_h = (short*)(ws + 18 * Q);    // Q18-23 (cat dead after xv1 gemm)
    short* xvh_l = (short*)(ws + 42 * Q);    // Q42-47 (vec2b dead after vdot_cat)
    // phase 4
    short* w1b   = (short*)(ws + 30 * Q);    // Q30-35 (bf16 3S; vec1 dead after e4)
    float* w2    = ws + 36 * Q;              // Q36-41 (fp32 3*NN*128)
    float* cat2  = ws + 42 * Q;              // Q42-49 (fp32 2S; xvh_l/vdot dead)
    float* t4    = ws + 18 * Q;              // Q18-21 (fp32 S; xvh_h dead)
    float* h1    = ws + 22 * Q;              // Q22-25 (fp32 S)
    float* x3    = ws + 26 * Q;              // Q26-27 (fp32 S/2)
    float* vecC  = ws + 28 * Q;              // Q28-33 (fp32 3*NN*128)
    // phase 5
    short* w3b   = (short*)(ws + 34 * Q);    // Q34-36 (bf16 3*NN*128)
    float* w4    = ws + 37 * Q;              // Q37
    float* cat3  = ws + 38 * Q;              // Q38-41 (fp32 NN*256)
    float* t5    = ws + 42 * Q;              // Q42-43

    // weight hi/lo offsets (shorts)
    short* WT_x1    = wtb;
    short* WT_x2    = wtb + 65536;
    short* WT_vp    = wtb + 262144;          // [n<512][k<256] contiguous -> fused vp
    short* WT_xv1   = wtb + 393216;
    short* WT_xv2   = wtb + 524288;
    short* WT_o1Wv1 = wtb + 720896;          // [n<256][k<256]; o1Wv2 follows -> fused N=384
    short* WT_o1Wv2 = wtb + 786432;
    short* WT_o1Wu1 = wtb + 819200;
    short* WT_o1Wu2 = wtb + 950272;
    short* WT_o2Wv1 = wtb + 1015808;
    short* WT_o2Wu1 = wtb + 1032192;
    short* WT_rbf   = wtb + 1064960;         // 768 x 64

    // Phase 0: all weight transposes + splits in one launch (incl. W_rbf^T)
    WtArgs wa;
    const float* wsrc[12] = {W_x1, W_x2, W_vp, W_xv1, W_xv2, o1_Wv1, o1_Wv2,
                             o1_Wu1, o1_Wu2, o2_Wv1, o2_Wu1, W_rbf};
    int wk[12] = {256, 256, 256, 512, 256, 256, 256, 512, 256, 128, 256, 64};
    int wn[12] = {256, 768, 512, 256, 768, 256, 128, 256, 256, 128, 128, 768};
    int off = 0;
    for (int i = 0; i < 12; i++) {
        wa.W[i] = wsrc[i]; wa.K[i] = wk[i]; wa.N[i] = wn[i];
        wa.off[i] = off; off += wk[i] * wn[i];
    }
    wa.off[12] = off;  // 1,114,112
    wt_split_all<<<off / 256, 256, 0, stream>>>(wa, wtb, wtb + WLO);

    // Phase 1: node MLP (+ x1/vecacc init; memcpy folded into ln_kernel)
    ln_kernel<<<NN, 256, 0, stream>>>(x, vec, ln_g, ln_b, xln, x1, vecacc);
    mfma_gemm<<<dim3(NN / 128, 4), 256, 0, stream>>>(xln, WT_x1, WT_x1 + WLO,
                                                     b_x1, t1, nullptr, NN, 256, 256, 1);
    mfma_gemm<<<dim3(NN / 128, 12), 256, 0, stream>>>(t1, WT_x2, WT_x2 + WLO,
                                                      b_x2, xh, nullptr, NN, 256, 768, 0);

    // Phase 2: sort edges by dst; edge-parallel fused gather (atomics)
    zero_kernel<<<(NN + 255) / 256, 256, 0, stream>>>(cursor, NN);
    hist_kernel<<<EE / 256, 256, 0, stream>>>(edge_index, cursor);
    scan_kernel<<<1, 256, 0, stream>>>(cursor, rowptr);
    scatter_kernel<<<EE / 256, 256, 0, stream>>>(edge_index, edge_vector, cursor,
                                                 perm, dsts, srcs, evs);
    edge_gather_kernel<<<EE / 128, 512, 0, stream>>>(
        edge_rbf, WT_rbf, WT_rbf + WLO, b_rbf, xh, vec,
        perm, dsts, srcs, evs, x1, vecacc);

    // Phase 3: fused vp (N=512: cols<256 -> fp32 vec1, >=256 -> bf16 vec2b)
    mfma_gemm<<<dim3(3 * NN / 128, 8), 256, 0, stream>>>(vecacc, WT_vp, WT_vp + WLO,
                                                         nullptr, vec1, vec2b,
                                                         3 * NN, 256, 512, 4);
    vdot_cat_kernel<<<NN, 256, 0, stream>>>(vec1, vec2b, x1, vdot, cat);
    mfma_gemm<<<dim3(NN / 128, 4), 256, 0, stream>>>(cat, WT_xv1, WT_xv1 + WLO,
                                                     b_xv1, t2, nullptr, NN, 512, 256, 1);
    mfma_gemm<<<dim3(NN / 128, 12), 256, 0, stream>>>(t2, WT_xv2, WT_xv2 + WLO,
                                                      b_xv2, xvh_h, xvh_l, NN, 256, 768, 3);
    e4_kernel<<<NN, 256, 0, stream>>>(x1, vecacc, vec1, vdot, xvh_h, xvh_l);

    // Phase 4: fused o1Wv (N=384: cols<256 -> bf16 w1b, >=256 -> fp32 w2)
    mfma_gemm<<<dim3(3 * NN / 128, 6), 256, 0, stream>>>(vecacc, WT_o1Wv1, WT_o1Wv1 + WLO,
                                                         nullptr, w1b, w2,
                                                         3 * NN, 256, 384, 5);
    normcat_kernel<<<NN * 512 / 256, 256, 0, stream>>>(x1, w1b, cat2, 256, 256, 9);
    mfma_gemm<<<dim3(NN / 128, 4), 256, 0, stream>>>(cat2, WT_o1Wu1, WT_o1Wu1 + WLO,
                                                     o1_bu1, t4, nullptr, NN, 512, 256, 1);
    mfma_gemm<<<dim3(NN / 128, 4), 256, 0, stream>>>(t4, WT_o1Wu2, WT_o1Wu2 + WLO,
                                                     o1_bu2, h1, nullptr, NN, 256, 256, 0);
    gate1_kernel<<<NN * 128 / 256, 256, 0, stream>>>(h1, w2, x3, vecC);

    // Phase 5: gated equivariant block 2 + output
    mfma_gemm<<<dim3(3 * NN / 128, 2), 256, 0, stream>>>(vecC, WT_o2Wv1, WT_o2Wv1 + WLO,
                                                         nullptr, w3b, nullptr,
                                                         3 * NN, 128, 128, 2);
    g12_kernel<<<3 * NN / 4, 256, 0, stream>>>(vecC, o2_Wv2, w4);
    normcat_kernel<<<NN * 256 / 256, 256, 0, stream>>>(x3, w3b, cat3, 128, 128, 8);
    mfma_gemm<<<dim3(NN / 128, 2), 256, 0, stream>>>(cat3, WT_o2Wu1, WT_o2Wu1 + WLO,
                                                     o2_bu1, t5, nullptr, NN, 256, 128, 1);
    final_kernel<<<NN / 4, 256, 0, stream>>>(t5, o2_Wu2, o2_bu2, w4, out);
}